// Round 13
// baseline (199.232 us; speedup 1.0000x reference)
//
#include <hip/hip_runtime.h>
#include <math.h>

#define B      256
#define QD     128
#define KD     64
#define NKEYS  1000000
#define TOPK   10
#define CAP    1024            // candidate slots per query (expect ~600)
#define KT     32              // keys per tile (8KB fp32 tile image)
#define NSUB   (NKEYS / KT)    // 31250 exactly
#define GRID   1024            // 4 blocks/CU exactly (thread-slot cap)
#define MARGIN 0.5f            // screening slack (>8 sigma of bf16 dot error)
#define LCAP   1024            // per-block LDS candidate stack (expect ~150)
#define RING   3

typedef __attribute__((ext_vector_type(8)))  short short8;
typedef __attribute__((ext_vector_type(16))) float f32x16;

// ---------------------------------------------------------------------------
// ws layout (bytes):
//   [0      ,  65536)  float  proj[B][KD]
//   [65536  ,  98304)  ushort pbf[B][KD]      (bf16 projected queries)
//   [98304  ,  99328)  float  tau[B]
//   [99328  , 100352)  int    cnt[B]
//   [100352 , 1148928) int    cidx[B][CAP]    (candidate key indices only)
// ---------------------------------------------------------------------------

__device__ inline unsigned short f2bf(float f) {  // RNE fp32 -> bf16
  unsigned u = __builtin_bit_cast(unsigned, f);
  u += 0x7fffu + ((u >> 16) & 1u);
  return (unsigned short)(u >> 16);
}

// Kernel 1: projection + tau + bf16 queries. One block per query, 64 threads.
__global__ __launch_bounds__(KD) void project_kernel(
    const float* __restrict__ q, const float* __restrict__ W,
    float* __restrict__ proj, unsigned short* __restrict__ pbf,
    float* __restrict__ tau, int* __restrict__ cnt) {
  const int b = blockIdx.x;
  const int j = threadIdx.x;
  const float* __restrict__ qrow = q + (size_t)b * QD;
  const float* __restrict__ wrow = W + (size_t)j * QD;
  float acc = 0.f;
#pragma unroll
  for (int i = 0; i < QD; i += 4) {
    float4 qv = *reinterpret_cast<const float4*>(qrow + i);
    float4 wv = *reinterpret_cast<const float4*>(wrow + i);
    acc = fmaf(qv.x, wv.x, acc);
    acc = fmaf(qv.y, wv.y, acc);
    acc = fmaf(qv.z, wv.z, acc);
    acc = fmaf(qv.w, wv.w, acc);
  }
  proj[b * KD + j] = acc;
  pbf[b * KD + j] = f2bf(acc);

  float ss = acc * acc;
#pragma unroll
  for (int off = 32; off; off >>= 1) ss += __shfl_xor(ss, off, 64);
  if (j == 0) {
    tau[b] = 3.3f * sqrtf(ss);  // ~600 expected candidates above tau-MARGIN
    cnt[b] = 0;
  }
}

// 8 fp32 -> short8 bf16 (truncation; err < 2^-8 rel, << MARGIN)
__device__ inline short8 pack_bf16x8(float4 a, float4 b) {
  union { uint4 u; short8 s; } cvt;
  cvt.u.x = __builtin_amdgcn_perm(__builtin_bit_cast(unsigned, a.y),
                                  __builtin_bit_cast(unsigned, a.x), 0x07060302u);
  cvt.u.y = __builtin_amdgcn_perm(__builtin_bit_cast(unsigned, a.w),
                                  __builtin_bit_cast(unsigned, a.z), 0x07060302u);
  cvt.u.z = __builtin_amdgcn_perm(__builtin_bit_cast(unsigned, b.y),
                                  __builtin_bit_cast(unsigned, b.x), 0x07060302u);
  cvt.u.w = __builtin_amdgcn_perm(__builtin_bit_cast(unsigned, b.w),
                                  __builtin_bit_cast(unsigned, b.z), 0x07060302u);
  return cvt.s;
}

// Async global->LDS, 16B per lane, linear dest (base + lane*16).
__device__ inline void gload_lds16(const float* g, unsigned char* l) {
  __builtin_amdgcn_global_load_lds(
      (const __attribute__((address_space(1))) unsigned*)g,
      (__attribute__((address_space(3))) unsigned*)l, 16, 0, 0);
}

// Kernel 2: bf16 MFMA screening -- r5 geometry + DMA ring + COUNTED vmcnt.
// 512 thr = 8 waves = all 256 queries (wave w: row-tile w); KT=32 keys/tile.
// Staging: global_load_lds into a 3-slot fp32 LDS ring -- zero staging VGPRs
// (full 4 blocks/CU occupancy), DMAs issued 2 tiles early, and the per-tile
// sync is `s_waitcnt vmcnt(1)` + raw s_barrier: tile t+1/t+2 loads stay IN
// FLIGHT across barriers (no vmcnt(0) drain -- the r2..r12 lockstep stall).
// Source addresses pre-swizzled (u ^= r&15) so linear-dest LDS reads are
// low-conflict; fp32->bf16 happens at fragment read (4 v_perm). Epilogue:
// wave-uniform tmin gate -> exact ltau check -> LDS stack -> one flush burst.
__global__ __launch_bounds__(512, 8) void screen_kernel(
    const float* __restrict__ keys, const unsigned short* __restrict__ pbf,
    const float* __restrict__ tau, int* __restrict__ cnt,
    int* __restrict__ cidx) {
  __shared__ __align__(16) unsigned char ring[RING][KT * KD * 4];  // 3x8KB
  __shared__ float ltau[B];
  __shared__ unsigned cand[LCAP];
  __shared__ int lcnt;
  const int tid = threadIdx.x;
  const int l   = tid & 63;
  const int w   = tid >> 6;   // wave 0..7 = query row-tile
  const int h   = l >> 5;
  const int ln  = l & 31;

  if (tid == 0) lcnt = 0;
  if (tid < B) ltau[tid] = tau[tid] - MARGIN;

  // Persistent A fragments: row = w*32+ln, k = 16s+8h+j (verified layout, r2).
  short8 afrag[4];
#pragma unroll
  for (int s = 0; s < 4; ++s)
    afrag[s] = *reinterpret_cast<const short8*>(
        (const char*)pbf + (w * 32 + ln) * 128 + s * 32 + h * 16);

  // Wave-uniform loose threshold: min over this wave's 32 queries.
  float tmin = tau[w * 32 + ln] - MARGIN;
#pragma unroll
  for (int off = 32; off; off >>= 1) tmin = fminf(tmin, __shfl_xor(tmin, off, 64));

  const int per = NSUB / GRID, rem = NSUB % GRID;
  const int b = blockIdx.x;
  const int t0 = b * per + (b < rem ? b : rem);
  const int t1 = t0 + per + (b < rem ? 1 : 0);

  // DMA source (per-lane, pre-swizzled): wave w covers 16B-slots
  // i = w*64+lane of the 512-slot tile image; r = i>>4 (key row), u = i&15;
  // linear slot (r,u) is filled from data chunk u^(r&15) of row r.
  const int r_ = (w * 64 + l) >> 4;
  const int u_ = l & 15;
  const int srcf = r_ * 64 + ((u_ ^ (r_ & 15)) << 2);  // float offset in tile
  // Wave-uniform LDS dest offset within a ring slot.
  const int dofs = w * 1024;

  // Read-side byte offsets: frag s, part p: data chunk k = 4s+2h+p of row ln
  // lives at slot k ^ (ln&15).
  int roff[4][2];
#pragma unroll
  for (int s = 0; s < 4; ++s)
#pragma unroll
    for (int p = 0; p < 2; ++p) {
      const int k = s * 4 + h * 2 + p;
      roff[s][p] = ln * 256 + ((k ^ (ln & 15)) << 4);
    }

  // Prologue: DMA tiles t0 -> slot0, t0+1 -> slot1.
  gload_lds16(keys + (size_t)t0 * 2048 + srcf, ring[0] + dofs);
  {
    const int tn = (t0 + 1 < t1) ? t0 + 1 : t1 - 1;
    gload_lds16(keys + (size_t)tn * 2048 + srcf, ring[1] + dofs);
  }
  __syncthreads();  // ltau/lcnt visible (drains prologue DMAs; startup only)

  for (int t = t0; t < t1; ++t) {
    // Counted wait: my newest DMA (t+1's) may stay in flight; t's must land.
    asm volatile("s_waitcnt vmcnt(1)" ::: "memory");
    __builtin_amdgcn_s_barrier();   // all waves' tile-t portions landed

    // Issue DMA for tile t+2 into the slot whose readers finished in iter t-1.
    const int tp = t + 2;
    const int tt = (tp < t1) ? tp : t1 - 1;  // tail: idempotent/dummy re-load
    gload_lds16(keys + (size_t)tt * 2048 + srcf,
                ring[(t - t0 + 2) % RING] + dofs);

    // Compute tile t from its ring slot (fp32 -> bf16 at read).
    const unsigned char* rb = ring[(t - t0) % RING];
    f32x16 acc;
#pragma unroll
    for (int r = 0; r < 16; ++r) acc[r] = 0.f;
#pragma unroll
    for (int s = 0; s < 4; ++s) {
      float4 fa = *reinterpret_cast<const float4*>(rb + roff[s][0]);
      float4 fb = *reinterpret_cast<const float4*>(rb + roff[s][1]);
      short8 bf = pack_bf16x8(fa, fb);
      acc = __builtin_amdgcn_mfma_f32_32x32x16_bf16(afrag[s], bf, acc, 0, 0, 0);
    }

    // Epilogue: wave-uniform tmin gate, exact ltau check on rare survivors.
    const int kb = t * KT + ln;
    float mx = acc[0];
#pragma unroll
    for (int r = 1; r < 16; ++r) mx = fmaxf(mx, acc[r]);
    if (mx > tmin) {
#pragma unroll
      for (int r = 0; r < 16; ++r) {
        if (acc[r] > tmin) {
          const int qq = w * 32 + (r & 3) + 8 * (r >> 2) + 4 * h;
          if (acc[r] > ltau[qq]) {
            int pos = atomicAdd(&lcnt, 1);
            if (pos < LCAP) cand[pos] = ((unsigned)qq << 20) | (unsigned)kb;
            else { int gp = atomicAdd(&cnt[qq], 1);
                   if (gp < CAP) cidx[qq * CAP + gp] = kb; }
          }
        }
      }
    }
  }

  __syncthreads();  // drains dangling tail DMAs; stack pushes visible
  // Flush: one parallel global-atomic burst per block (~150 candidates).
  int m = lcnt; if (m > LCAP) m = LCAP;
  for (int i = tid; i < m; i += 512) {
    const unsigned c = cand[i];
    const int qq = c >> 20, key = c & 0xFFFFF;
    int pos = atomicAdd(&cnt[qq], 1);
    if (pos < CAP) cidx[qq * CAP + pos] = key;
  }
}

// Kernel 3 (fused): exact fp32 rescore into LDS, then exact top-10.
// One block per query, 256 threads = 4 waves.
__global__ __launch_bounds__(256) void finalize_kernel(
    const float* __restrict__ keys, const float* __restrict__ proj,
    const int* __restrict__ cnt, const int* __restrict__ cidx,
    const int* __restrict__ doc_ids, float* __restrict__ out) {
  __shared__ float p[KD];
  __shared__ float ls[CAP];
  __shared__ int   li[CAP];
  __shared__ float rbest[4];
  __shared__ int   rbidx[4], rbpos[4];
  const int q = blockIdx.x;
  const int tid = threadIdx.x;
  const int lane = tid & 63, wv = tid >> 6;

  if (tid < KD) p[tid] = proj[q * KD + tid];
  int n = cnt[q]; if (n > CAP) n = CAP;
  __syncthreads();

  // Rescore: exact fp32, same accumulation order as the reference-validated r1.
  for (int i = tid; i < n; i += 256) {
    const int key = cidx[q * CAP + i];
    const float4* kp = reinterpret_cast<const float4*>(keys + (size_t)key * KD);
    float a0 = 0.f, a1 = 0.f, a2 = 0.f, a3 = 0.f;
#pragma unroll
    for (int c = 0; c < KD / 4; ++c) {
      float4 kv = kp[c];
      a0 = fmaf(kv.x, p[4 * c + 0], a0);
      a1 = fmaf(kv.y, p[4 * c + 1], a1);
      a2 = fmaf(kv.z, p[4 * c + 2], a2);
      a3 = fmaf(kv.w, p[4 * c + 3], a3);
    }
    ls[i] = (a0 + a1) + (a2 + a3);
    li[i] = key;
  }
  __syncthreads();

  // Top-10: iterated argmax, (score desc, idx asc) — deterministic.
  for (int r = 0; r < TOPK; ++r) {
    float best = -__builtin_inff();
    int bidx = 0x7fffffff, bpos = -1;
    for (int i = tid; i < n; i += 256) {
      float s = ls[i]; int ii = li[i];
      if (s > best || (s == best && ii < bidx)) { best = s; bidx = ii; bpos = i; }
    }
#pragma unroll
    for (int off = 32; off; off >>= 1) {
      float os = __shfl_xor(best, off, 64);
      int oi = __shfl_xor(bidx, off, 64);
      int op = __shfl_xor(bpos, off, 64);
      if (os > best || (os == best && oi < bidx)) { best = os; bidx = oi; bpos = op; }
    }
    if (lane == 0) { rbest[wv] = best; rbidx[wv] = bidx; rbpos[wv] = bpos; }
    __syncthreads();
    if (tid == 0) {
#pragma unroll
      for (int k = 1; k < 4; ++k) {
        if (rbest[k] > best || (rbest[k] == best && rbidx[k] < bidx)) {
          best = rbest[k]; bidx = rbidx[k]; bpos = rbpos[k];
        }
      }
      out[q * TOPK + r] = (float)((bpos >= 0) ? doc_ids[bidx] : 0);
      out[B * TOPK + q * TOPK + r] = best;
      if (bpos >= 0) ls[bpos] = -__builtin_inff();
    }
    __syncthreads();
  }
}

extern "C" void kernel_launch(void* const* d_in, const int* in_sizes, int n_in,
                              void* d_out, int out_size, void* d_ws, size_t ws_size,
                              hipStream_t stream) {
  const float* queries = (const float*)d_in[0];
  const float* W       = (const float*)d_in[1];
  const float* keys    = (const float*)d_in[2];
  const int*   doc_ids = (const int*)d_in[3];
  float* out = (float*)d_out;

  char* ws = (char*)d_ws;
  float*          proj = (float*)(ws + 0);
  unsigned short* pbf  = (unsigned short*)(ws + 65536);
  float*          tau  = (float*)(ws + 98304);
  int*            cnt  = (int*)(ws + 99328);
  int*            cidx = (int*)(ws + 100352);

  project_kernel<<<B, KD, 0, stream>>>(queries, W, proj, pbf, tau, cnt);
  screen_kernel<<<GRID, 512, 0, stream>>>(keys, pbf, tau, cnt, cidx);
  finalize_kernel<<<B, 256, 0, stream>>>(keys, proj, cnt, cidx, doc_ids, out);
}